// Round 3
// baseline (1080.254 us; speedup 1.0000x reference)
//
#include <hip/hip_runtime.h>

// GraphSelfAttention: E3NN-style graph attention.
// N=20000 nodes, E=120000 edges, MUL0=16, MUL1=8, NB=10, DK=16, DV=32.
// Round 3: 4 threads per edge (c-split) for occupancy; sparse radial basis.

#define MUL0 16
#define MUL1 8
#define NBASIS 10
#define DK 16
#define DV 32
#define XDIM 40   // MUL0 + 3*MUL1

#define CC 26.6692987f          // 1.14136 * e^2 * sqrt(10)
#define INV_SQRT10 0.3162277660f
#define KV_SCALE 0.0510310363f  // 1/(4*sqrt(24))

__global__ void node_qd_kernel(const float* __restrict__ x,
                               const float* __restrict__ Wq,
                               const float* __restrict__ Wdot,
                               float* __restrict__ qd, int N) {
    int n = blockIdx.x * blockDim.x + threadIdx.x;
    if (n >= N) return;
    const float* xr = x + (size_t)n * XDIM;
    float x0[MUL0];
#pragma unroll
    for (int u = 0; u < MUL0; ++u) x0[u] = xr[u];
    float q[DK];
#pragma unroll
    for (int w = 0; w < DK; ++w) {
        float a = 0.f;
#pragma unroll
        for (int u = 0; u < MUL0; ++u) a += x0[u] * Wq[u * DK + w];
        q[w] = a * 0.25f;  // /sqrt(16)
    }
#pragma unroll
    for (int w = 0; w < DK; ++w) {
        float a = 0.f;
#pragma unroll
        for (int u = 0; u < DK; ++u) a += q[u] * Wdot[u * DK + w];
        qd[(size_t)n * DK + w] = a * 0.0625f;  // /MUL0
    }
}

// 4 threads per edge; thread q in [0,4) handles channels c = 4q..4q+3.
__global__ __launch_bounds__(256) void edge_kernel(
    const float* __restrict__ x, const float* __restrict__ pos,
    const float* __restrict__ Wk1, const float* __restrict__ Wk2,
    const float* __restrict__ Wv1, const float* __restrict__ Wv2,
    const float* __restrict__ qd,
    const int* __restrict__ esrc, const int* __restrict__ edst,
    float* __restrict__ zbuf, float* __restrict__ expvbuf,
    float* __restrict__ vbuf, int* __restrict__ deg, int E) {
    int t = blockIdx.x * blockDim.x + threadIdx.x;
    int e = t >> 2;
    int q = t & 3;
    if (e >= E) return;
    int s = esrc[e];
    int d = edst[e];

    if (q == 0) atomicAdd(&deg[d], 1);  // histogram for CSR build

    float ev0 = pos[s * 3 + 0] - pos[d * 3 + 0];
    float ev1 = pos[s * 3 + 1] - pos[d * 3 + 1];
    float ev2 = pos[s * 3 + 2] - pos[d * 3 + 2];
    float len2 = ev0 * ev0 + ev1 * ev1 + ev2 * ev2 + 1e-12f;
    float elen = sqrtf(len2);
    float inv = 1.0f / elen;

    // Radial basis has support width 2 in t = elen/step: at most 2 non-zero
    // components, indices floor(t)-1 and floor(t).
    float tt = elen * 2.75f;  // elen / (4/11)
    int fi = (int)floorf(tt);
    int ia = fi - 1, ib = fi;
    float ea = 0.f, eb = 0.f;
    {
        float a = tt - (float)ia, b = (float)(ia + 2) - tt;
        if (ia >= 0 && ia < NBASIS && a > 0.f && b > 0.f)
            ea = CC * expf(-1.f / a - 1.f / b);
    }
    {
        float a = tt - (float)ib, b = (float)(ib + 2) - tt;
        if (ib >= 0 && ib < NBASIS && b > 0.f && a > 0.f)
            eb = CC * expf(-1.f / a - 1.f / b);
    }
    int ja = (ia >= 0 && ia < NBASIS) ? ia : 0;  // safe row (ea==0 if invalid)
    int jb = (ib >= 0 && ib < NBASIS) ? ib : 0;

    // h_k, h_v = silu((emb @ W1) / sqrt(10)) for this thread's 4 channels
    float hk4[4], hv4[4];
#pragma unroll
    for (int cl = 0; cl < 4; ++cl) {
        int c = 4 * q + cl;
        float ak = (ea * Wk1[ja * 16 + c] + eb * Wk1[jb * 16 + c]) * INV_SQRT10;
        float av = (ea * Wv1[ja * 16 + c] + eb * Wv1[jb * 16 + c]) * INV_SQRT10;
        hk4[cl] = ak / (1.f + expf(-ak));
        hv4[cl] = av / (1.f + expf(-av));
    }

    // f = [x0_src (16), x1dot (8)]
    float f[24];
    const float* xr = x + (size_t)s * XDIM;
#pragma unroll
    for (int u = 0; u < MUL0; ++u) f[u] = xr[u];
#pragma unroll
    for (int u = 0; u < MUL1; ++u) {
        f[MUL0 + u] = (xr[16 + u * 3 + 0] * ev0 + xr[16 + u * 3 + 1] * ev1 +
                       xr[16 + u * 3 + 2] * ev2) * inv;
    }

    float kk[DK];
    float vv[DV];
#pragma unroll
    for (int w = 0; w < DK; ++w) kk[w] = 0.f;
#pragma unroll
    for (int w = 0; w < DV; ++w) vv[w] = 0.f;

    for (int cl = 0; cl < 4; ++cl) {
        int c = 4 * q + cl;
        float tk = hk4[cl];
        float tv = hv4[cl];
        const float* __restrict__ wkrow = Wk2 + c * 384;
        const float* __restrict__ wvrow = Wv2 + c * 768;
        for (int u = 0; u < 24; ++u) {
            float gk = tk * f[u];
            float gv = tv * f[u];
#pragma unroll
            for (int w = 0; w < DK; ++w) kk[w] += gk * wkrow[u * 16 + w];
#pragma unroll
            for (int w = 0; w < DV; ++w) vv[w] += gv * wvrow[u * 32 + w];
        }
    }

    // Butterfly-reduce partials across the 4-lane group (all lanes get sums).
#pragma unroll
    for (int m = 1; m <= 2; m <<= 1) {
#pragma unroll
        for (int w = 0; w < DK; ++w) kk[w] += __shfl_xor(kk[w], m);
#pragma unroll
        for (int w = 0; w < DV; ++w) vv[w] += __shfl_xor(vv[w], m);
    }

    if (q == 0) {  // leader: logit, expv, stores (static reg indexing only)
        const float* qdr = qd + (size_t)d * DK;
        float logit = 0.f;
#pragma unroll
        for (int w = 0; w < DK; ++w) logit += qdr[w] * kk[w];
        logit *= KV_SCALE;

        float arg = 10.f - 2.5f * elen;  // 10*(1 - elen/RMAX)
        float wcut = (arg > 0.f) ? expf(-1.f / arg) : 0.f;
        float expv = wcut * expf(logit);

        expvbuf[e] = expv;
        if (expv != 0.f) atomicAdd(&zbuf[d], expv);

        float* vr = vbuf + (size_t)e * DV;
#pragma unroll
        for (int w = 0; w < DV; ++w) vr[w] = vv[w] * KV_SCALE;
    }
}

// Single-block exclusive scan of deg[0..N) -> start[0..N], start[N] = total.
__global__ __launch_bounds__(1024) void scan_kernel(const int* __restrict__ deg,
                                                    int* __restrict__ start, int N) {
    __shared__ int lds[1024];
    const int tid = threadIdx.x;
    const int chunk = (N + 1023) / 1024;
    const int lo = tid * chunk;
    const int hi = min(N, lo + chunk);
    int s = 0;
    for (int i = lo; i < hi; ++i) s += deg[i];
    lds[tid] = s;
    __syncthreads();
    for (int off = 1; off < 1024; off <<= 1) {
        int v = (tid >= off) ? lds[tid - off] : 0;
        __syncthreads();
        lds[tid] += v;
        __syncthreads();
    }
    int running = lds[tid] - s;  // exclusive base for this chunk
    for (int i = lo; i < hi; ++i) {
        start[i] = running;
        running += deg[i];
    }
    if (tid == 1023) start[N] = lds[1023];
}

__global__ void fill_kernel(const int* __restrict__ edst,
                            const int* __restrict__ start,
                            int* __restrict__ cursor,
                            int* __restrict__ bucket, int E) {
    int e = blockIdx.x * blockDim.x + threadIdx.x;
    if (e >= E) return;
    int d = edst[e];
    int p = atomicAdd(&cursor[d], 1);
    bucket[start[d] + p] = e;
}

// 32 lanes per node, one lane per output column. No atomics.
__global__ __launch_bounds__(256) void gather_kernel(
    const float* __restrict__ expvbuf, const float* __restrict__ vbuf,
    const float* __restrict__ zbuf, const int* __restrict__ start,
    const int* __restrict__ bucket, float* __restrict__ out, int N) {
    int n = blockIdx.x * 8 + (threadIdx.x >> 5);
    int w = threadIdx.x & 31;
    if (n >= N) return;
    float z = zbuf[n];
    if (z == 0.f) z = 1.f;
    float rz = 1.0f / z;
    int lo = start[n], hi = start[n + 1];
    float acc = 0.f;
    for (int i = lo; i < hi; ++i) {
        int e = bucket[i];                 // broadcast across 32 lanes
        float ev = expvbuf[e];             // broadcast
        float sa = sqrtf(ev * rz);
        acc += sa * vbuf[(size_t)e * DV + w];  // coalesced across lanes
    }
    out[(size_t)n * DV + w] = acc;
}

extern "C" void kernel_launch(void* const* d_in, const int* in_sizes, int n_in,
                              void* d_out, int out_size, void* d_ws, size_t ws_size,
                              hipStream_t stream) {
    const float* x    = (const float*)d_in[0];
    const float* pos  = (const float*)d_in[1];
    const float* Wq   = (const float*)d_in[2];
    const float* Wk1  = (const float*)d_in[3];
    const float* Wk2  = (const float*)d_in[4];
    const float* Wv1  = (const float*)d_in[5];
    const float* Wv2  = (const float*)d_in[6];
    const float* Wdot = (const float*)d_in[7];
    const int* esrc   = (const int*)d_in[8];
    const int* edst   = (const int*)d_in[9];

    const int N = in_sizes[0] / XDIM;
    const int E = in_sizes[8];

    float* out = (float*)d_out;

    // workspace layout (all 4-byte elements)
    float* qd      = (float*)d_ws;              // N*16
    float* zbuf    = qd + (size_t)N * DK;       // N      } contiguous zero
    int*   deg     = (int*)(zbuf + N);          // N      } block: one
    int*   cursor  = deg + N;                   // N      } memset
    int*   start   = cursor + N;                // N+1
    int*   bucket  = start + N + 1;             // E
    float* expvbuf = (float*)(bucket + E);      // E
    float* vbuf    = expvbuf + E;               // E*32

    hipMemsetAsync(zbuf, 0, (size_t)(3 * N) * sizeof(int), stream);

    {
        int bs = 256, gs = (N + bs - 1) / bs;
        node_qd_kernel<<<gs, bs, 0, stream>>>(x, Wq, Wdot, qd, N);
    }
    {
        int bs = 256, gs = (4 * E + bs - 1) / bs;
        edge_kernel<<<gs, bs, 0, stream>>>(x, pos, Wk1, Wk2, Wv1, Wv2, qd,
                                           esrc, edst, zbuf, expvbuf, vbuf, deg, E);
    }
    scan_kernel<<<1, 1024, 0, stream>>>(deg, start, N);
    {
        int bs = 256, gs = (E + bs - 1) / bs;
        fill_kernel<<<gs, bs, 0, stream>>>(edst, start, cursor, bucket, E);
    }
    {
        int bs = 256, gs = (N + 7) / 8;
        gather_kernel<<<gs, bs, 0, stream>>>(expvbuf, vbuf, zbuf, start, bucket, out, N);
    }
}

// Round 4
// 179.260 us; speedup vs baseline: 6.0262x; 6.0262x over previous
//
#include <hip/hip_runtime.h>

// GraphSelfAttention: E3NN-style graph attention.
// N=20000 nodes, E=120000 edges, MUL0=16, MUL1=8, NB=10, DK=16, DV=32.
// Round 4: c-split across WAVES (not lanes!) to keep weight addresses
// wave-uniform (s_load path), 4x wave count; LDS cross-wave reduction.
// Round-3 lesson: lane-dependent c demoted s_load->global_load (SGPR 112->48),
// 5x regression. The c-axis may only be split across waves.

#define MUL0 16
#define MUL1 8
#define NBASIS 10
#define DK 16
#define DV 32
#define XDIM 40   // MUL0 + 3*MUL1

#define CC 26.6692987f          // 1.14136 * e^2 * sqrt(10)
#define INV_SQRT10 0.3162277660f
#define KV_SCALE 0.0510310363f  // 1/(4*sqrt(24))

__global__ void node_qd_kernel(const float* __restrict__ x,
                               const float* __restrict__ Wq,
                               const float* __restrict__ Wdot,
                               float* __restrict__ qd, int N) {
    int n = blockIdx.x * blockDim.x + threadIdx.x;
    if (n >= N) return;
    const float* xr = x + (size_t)n * XDIM;
    float x0[MUL0];
#pragma unroll
    for (int u = 0; u < MUL0; ++u) x0[u] = xr[u];
    float q[DK];
#pragma unroll
    for (int w = 0; w < DK; ++w) {
        float a = 0.f;
#pragma unroll
        for (int u = 0; u < MUL0; ++u) a += x0[u] * Wq[u * DK + w];
        q[w] = a * 0.25f;  // /sqrt(16)
    }
#pragma unroll
    for (int w = 0; w < DK; ++w) {
        float a = 0.f;
#pragma unroll
        for (int u = 0; u < DK; ++u) a += q[u] * Wdot[u * DK + w];
        qd[(size_t)n * DK + w] = a * 0.0625f;  // /MUL0
    }
}

// Block = 256 threads = 4 waves; block owns 64 edges (lane <-> edge).
// Wave w computes channels c in [4w, 4w+4) -- c is WAVE-uniform.
__global__ __launch_bounds__(256) void edge_kernel(
    const float* __restrict__ x, const float* __restrict__ pos,
    const float* __restrict__ Wk1, const float* __restrict__ Wk2,
    const float* __restrict__ Wv1, const float* __restrict__ Wv2,
    const float* __restrict__ qd,
    const int* __restrict__ esrc, const int* __restrict__ edst,
    float* __restrict__ zbuf, float* __restrict__ expvbuf,
    float* __restrict__ vbuf, int* __restrict__ deg, int E) {
    __shared__ float red[3][64][49];  // partials from waves 1..3; stride 49
                                      // -> bank 17*l+i, 17 odd: conflict-free

    const int lane = threadIdx.x & 63;
    // Pin wave id to SGPR so c-derived weight addresses are provably uniform.
    const int w4 = __builtin_amdgcn_readfirstlane(threadIdx.x >> 6);
    const int e = blockIdx.x * 64 + lane;
    const bool valid = (e < E);

    int s = 0, d = 0;
    if (valid) { s = esrc[e]; d = edst[e]; }

    float ev0 = 0.f, ev1 = 0.f, ev2 = 0.f;
    if (valid) {
        ev0 = pos[s * 3 + 0] - pos[d * 3 + 0];
        ev1 = pos[s * 3 + 1] - pos[d * 3 + 1];
        ev2 = pos[s * 3 + 2] - pos[d * 3 + 2];
    }
    float len2 = ev0 * ev0 + ev1 * ev1 + ev2 * ev2 + 1e-12f;
    float elen = sqrtf(len2);
    float inv = 1.0f / elen;

    // Radial basis: support width 2 -> at most 2 non-zero components.
    float tt = elen * 2.75f;  // elen / (4/11)
    int fi = (int)floorf(tt);
    int ia = fi - 1, ib = fi;
    float ea = 0.f, eb = 0.f;
    {
        float a = tt - (float)ia, b = (float)(ia + 2) - tt;
        if (ia >= 0 && ia < NBASIS && a > 0.f && b > 0.f)
            ea = CC * expf(-1.f / a - 1.f / b);
    }
    {
        float a = tt - (float)ib, b = (float)(ib + 2) - tt;
        if (ib >= 0 && ib < NBASIS && b > 0.f && a > 0.f)
            eb = CC * expf(-1.f / a - 1.f / b);
    }
    int ja = (ia >= 0 && ia < NBASIS) ? ia : 0;  // safe row (ea==0 if invalid)
    int jb = (ib >= 0 && ib < NBASIS) ? ib : 0;

    // This wave's 4 hidden activations (c = 4*w4+cl is wave-uniform; Wk1
    // row index ja/jb is per-lane -> small vector loads, fine).
    float hk4[4], hv4[4];
#pragma unroll
    for (int cl = 0; cl < 4; ++cl) {
        int c = 4 * w4 + cl;
        float ak = (ea * Wk1[ja * 16 + c] + eb * Wk1[jb * 16 + c]) * INV_SQRT10;
        float av = (ea * Wv1[ja * 16 + c] + eb * Wv1[jb * 16 + c]) * INV_SQRT10;
        hk4[cl] = ak / (1.f + expf(-ak));
        hv4[cl] = av / (1.f + expf(-av));
    }

    // f = [x0_src (16), x1dot (8)]  (recomputed by all 4 waves; ~100 VALU)
    float f[24];
    const float* xr = x + (size_t)s * XDIM;
    if (valid) {
#pragma unroll
        for (int u = 0; u < MUL0; ++u) f[u] = xr[u];
#pragma unroll
        for (int u = 0; u < MUL1; ++u) {
            f[MUL0 + u] = (xr[16 + u * 3 + 0] * ev0 + xr[16 + u * 3 + 1] * ev1 +
                           xr[16 + u * 3 + 2] * ev2) * inv;
        }
    } else {
#pragma unroll
        for (int u = 0; u < 24; ++u) f[u] = 0.f;
    }

    float kk[DK];
    float vv[DV];
#pragma unroll
    for (int w = 0; w < DK; ++w) kk[w] = 0.f;
#pragma unroll
    for (int w = 0; w < DV; ++w) vv[w] = 0.f;

#pragma unroll
    for (int cl = 0; cl < 4; ++cl) {
        int c = 4 * w4 + cl;  // wave-uniform -> weight rows via s_load
        float tk = hk4[cl];
        float tv = hv4[cl];
        const float* __restrict__ wkrow = Wk2 + c * 384;
        const float* __restrict__ wvrow = Wv2 + c * 768;
        for (int u = 0; u < 24; ++u) {
            float gk = tk * f[u];
            float gv = tv * f[u];
#pragma unroll
            for (int w = 0; w < DK; ++w) kk[w] += gk * wkrow[u * 16 + w];
#pragma unroll
            for (int w = 0; w < DV; ++w) vv[w] += gv * wvrow[u * 32 + w];
        }
    }

    // Cross-wave reduction: waves 1..3 dump partials; wave 0 sums + epilogue.
    if (w4 > 0) {
#pragma unroll
        for (int w = 0; w < DK; ++w) red[w4 - 1][lane][w] = kk[w];
#pragma unroll
        for (int w = 0; w < DV; ++w) red[w4 - 1][lane][DK + w] = vv[w];
    }
    __syncthreads();
    if (w4 == 0 && valid) {
#pragma unroll
        for (int r = 0; r < 3; ++r) {
#pragma unroll
            for (int w = 0; w < DK; ++w) kk[w] += red[r][lane][w];
#pragma unroll
            for (int w = 0; w < DV; ++w) vv[w] += red[r][lane][DK + w];
        }

        atomicAdd(&deg[d], 1);  // histogram for CSR build

        const float* qdr = qd + (size_t)d * DK;
        float logit = 0.f;
#pragma unroll
        for (int w = 0; w < DK; ++w) logit += qdr[w] * kk[w];
        logit *= KV_SCALE;

        float arg = 10.f - 2.5f * elen;  // 10*(1 - elen/RMAX)
        float wcut = (arg > 0.f) ? expf(-1.f / arg) : 0.f;
        float expv = wcut * expf(logit);

        expvbuf[e] = expv;
        if (expv != 0.f) atomicAdd(&zbuf[d], expv);

        float* vr = vbuf + (size_t)e * DV;
#pragma unroll
        for (int w = 0; w < DV; ++w) vr[w] = vv[w] * KV_SCALE;
    }
}

// Single-block exclusive scan of deg[0..N) -> start[0..N], start[N] = total.
__global__ __launch_bounds__(1024) void scan_kernel(const int* __restrict__ deg,
                                                    int* __restrict__ start, int N) {
    __shared__ int lds[1024];
    const int tid = threadIdx.x;
    const int chunk = (N + 1023) / 1024;
    const int lo = tid * chunk;
    const int hi = min(N, lo + chunk);
    int s = 0;
    for (int i = lo; i < hi; ++i) s += deg[i];
    lds[tid] = s;
    __syncthreads();
    for (int off = 1; off < 1024; off <<= 1) {
        int v = (tid >= off) ? lds[tid - off] : 0;
        __syncthreads();
        lds[tid] += v;
        __syncthreads();
    }
    int running = lds[tid] - s;  // exclusive base for this chunk
    for (int i = lo; i < hi; ++i) {
        start[i] = running;
        running += deg[i];
    }
    if (tid == 1023) start[N] = lds[1023];
}

__global__ void fill_kernel(const int* __restrict__ edst,
                            const int* __restrict__ start,
                            int* __restrict__ cursor,
                            int* __restrict__ bucket, int E) {
    int e = blockIdx.x * blockDim.x + threadIdx.x;
    if (e >= E) return;
    int d = edst[e];
    int p = atomicAdd(&cursor[d], 1);
    bucket[start[d] + p] = e;
}

// 32 lanes per node, one lane per output column. No atomics.
__global__ __launch_bounds__(256) void gather_kernel(
    const float* __restrict__ expvbuf, const float* __restrict__ vbuf,
    const float* __restrict__ zbuf, const int* __restrict__ start,
    const int* __restrict__ bucket, float* __restrict__ out, int N) {
    int n = blockIdx.x * 8 + (threadIdx.x >> 5);
    int w = threadIdx.x & 31;
    if (n >= N) return;
    float z = zbuf[n];
    if (z == 0.f) z = 1.f;
    float rz = 1.0f / z;
    int lo = start[n], hi = start[n + 1];
    float acc = 0.f;
    for (int i = lo; i < hi; ++i) {
        int e = bucket[i];                 // broadcast across 32 lanes
        float ev = expvbuf[e];             // broadcast
        float sa = sqrtf(ev * rz);
        acc += sa * vbuf[(size_t)e * DV + w];  // coalesced across lanes
    }
    out[(size_t)n * DV + w] = acc;
}

extern "C" void kernel_launch(void* const* d_in, const int* in_sizes, int n_in,
                              void* d_out, int out_size, void* d_ws, size_t ws_size,
                              hipStream_t stream) {
    const float* x    = (const float*)d_in[0];
    const float* pos  = (const float*)d_in[1];
    const float* Wq   = (const float*)d_in[2];
    const float* Wk1  = (const float*)d_in[3];
    const float* Wk2  = (const float*)d_in[4];
    const float* Wv1  = (const float*)d_in[5];
    const float* Wv2  = (const float*)d_in[6];
    const float* Wdot = (const float*)d_in[7];
    const int* esrc   = (const int*)d_in[8];
    const int* edst   = (const int*)d_in[9];

    const int N = in_sizes[0] / XDIM;
    const int E = in_sizes[8];

    float* out = (float*)d_out;

    // workspace layout (all 4-byte elements)
    float* qd      = (float*)d_ws;              // N*16
    float* zbuf    = qd + (size_t)N * DK;       // N      } contiguous zero
    int*   deg     = (int*)(zbuf + N);          // N      } block: one
    int*   cursor  = deg + N;                   // N      } memset
    int*   start   = cursor + N;                // N+1
    int*   bucket  = start + N + 1;             // E
    float* expvbuf = (float*)(bucket + E);      // E
    float* vbuf    = expvbuf + E;               // E*32

    hipMemsetAsync(zbuf, 0, (size_t)(3 * N) * sizeof(int), stream);

    {
        int bs = 256, gs = (N + bs - 1) / bs;
        node_qd_kernel<<<gs, bs, 0, stream>>>(x, Wq, Wdot, qd, N);
    }
    {
        // one block per 64 edges; 4 waves split the hidden-channel axis
        int gs = (E + 63) / 64;
        edge_kernel<<<gs, 256, 0, stream>>>(x, pos, Wk1, Wk2, Wv1, Wv2, qd,
                                            esrc, edst, zbuf, expvbuf, vbuf, deg, E);
    }
    scan_kernel<<<1, 1024, 0, stream>>>(deg, start, N);
    {
        int bs = 256, gs = (E + bs - 1) / bs;
        fill_kernel<<<gs, bs, 0, stream>>>(edst, start, cursor, bucket, E);
    }
    {
        int bs = 256, gs = (N + 7) / 8;
        gather_kernel<<<gs, bs, 0, stream>>>(expvbuf, vbuf, zbuf, start, bucket, out, N);
    }
}

// Round 5
// 120.684 us; speedup vs baseline: 8.9511x; 1.4854x over previous
//
#include <hip/hip_runtime.h>

// GraphSelfAttention: E3NN-style graph attention.
// N=20000 nodes, E=120000 edges, MUL0=16, MUL1=8, NB=10, DK=16, DV=32.
// Round 5: MFMA-ized edge kernel. k/v = G x B with G[e,(c,u)] = h[c]*f[u],
// B = reshaped Wk2/Wv2 [384 x 48] staged in LDS (bf16, n-major, XOR-swizzled).
// K-order chosen as k' = s*32+g*8+i <-> (c = 4(s&3)+g, u = 8(s>>2)+i) so the
// f-octet is compile-time and h needs only 4 values per lane.
// K-path is hi/lo error-compensated (3 MFMAs); V-path plain bf16.

#define MUL0 16
#define MUL1 8
#define NBASIS 10
#define DK 16
#define DV 32
#define XDIM 40   // MUL0 + 3*MUL1

#define CC 26.6692987f          // 1.14136 * e^2 * sqrt(10)
#define INV_SQRT10 0.3162277660f
#define KV_SCALE 0.0510310363f  // 1/(4*sqrt(24))

typedef short short8 __attribute__((ext_vector_type(8)));
typedef float f32x4 __attribute__((ext_vector_type(4)));

union Frag { int i[4]; short8 v; };

template <int N> struct IC { static constexpr int value = N; };

__device__ __forceinline__ float hi_part(float x) {
    unsigned u = __builtin_bit_cast(unsigned, x) & 0xFFFF0000u;
    return __builtin_bit_cast(float, u);
}
// pack {lo16=a>>16, hi16=b>>16} via byte-perm (truncation to bf16)
__device__ __forceinline__ int pack_trunc(float a, float b) {
    return (int)__builtin_amdgcn_perm(__builtin_bit_cast(unsigned, b),
                                      __builtin_bit_cast(unsigned, a),
                                      0x07060302u);
}

__global__ void node_qd_kernel(const float* __restrict__ x,
                               const float* __restrict__ Wq,
                               const float* __restrict__ Wdot,
                               float* __restrict__ qd, int N) {
    int n = blockIdx.x * blockDim.x + threadIdx.x;
    if (n >= N) return;
    const float* xr = x + (size_t)n * XDIM;
    float x0[MUL0];
#pragma unroll
    for (int u = 0; u < MUL0; ++u) x0[u] = xr[u];
    float q[DK];
#pragma unroll
    for (int w = 0; w < DK; ++w) {
        float a = 0.f;
#pragma unroll
        for (int u = 0; u < MUL0; ++u) a += x0[u] * Wq[u * DK + w];
        q[w] = a * 0.25f;  // /sqrt(16)
    }
#pragma unroll
    for (int w = 0; w < DK; ++w) {
        float a = 0.f;
#pragma unroll
        for (int u = 0; u < DK; ++u) a += q[u] * Wdot[u * DK + w];
        qd[(size_t)n * DK + w] = a * 0.0625f;  // /MUL0
    }
}

// Block = 256 threads = 4 waves; block owns 64 edges (wave owns a 16-edge
// M-tile). A-frag row m = lane&15 (edge), k-group g = lane>>4.
__global__ __launch_bounds__(256) void edge_kernel(
    const float* __restrict__ x, const float* __restrict__ pos,
    const float* __restrict__ Wk1, const float* __restrict__ Wk2,
    const float* __restrict__ Wv1, const float* __restrict__ Wv2,
    const float* __restrict__ qd,
    const int* __restrict__ esrc, const int* __restrict__ edst,
    float* __restrict__ zbuf, float* __restrict__ expvbuf,
    float* __restrict__ vbuf, int* __restrict__ deg, int E) {
    __shared__ char BkHi[16 * 384 * 2];   // 12 KB  [n][384 k'] bf16, swizzled
    __shared__ char BkLo[16 * 384 * 2];   // 12 KB
    __shared__ char BvL[32 * 384 * 2];    // 24 KB
    __shared__ int dst_lds[64];
    __shared__ float wcut_lds[64];

    const int tid = threadIdx.x;
    const int wv = tid >> 6;        // wave 0..3
    const int lane = tid & 63;
    const int mrow = lane & 15;     // edge row within tile / output col
    const int g = lane >> 4;        // k-group

    // ---------------- B staging (whole block) ----------------
    // Bk: element (n, k'=2kp,2kp+1): c = 4(s&3)+g2, u = 8(s>>2)+i2
    for (int i = tid; i < 3072; i += 256) {
        int n = i & 15, kp = i >> 4;             // kp in [0,192)
        int s = kp >> 4, g2 = (kp >> 2) & 3, i2 = (kp & 3) * 2;
        int c = 4 * (s & 3) + g2;
        int u = 8 * (s >> 2) + i2;
        float w0 = Wk2[c * 384 + u * 16 + n];
        float w1 = Wk2[c * 384 + (u + 1) * 16 + n];
        int byo = (n * 768 + kp * 4) ^ ((n & 7) << 4);
        *(int*)(BkHi + byo) = pack_trunc(w0, w1);
        *(int*)(BkLo + byo) = pack_trunc(w0 - hi_part(w0), w1 - hi_part(w1));
    }
    for (int i = tid; i < 6144; i += 256) {
        int n = i & 31, kp = i >> 5;
        int s = kp >> 4, g2 = (kp >> 2) & 3, i2 = (kp & 3) * 2;
        int c = 4 * (s & 3) + g2;
        int u = 8 * (s >> 2) + i2;
        float w0 = Wv2[c * 768 + u * 32 + n];
        float w1 = Wv2[c * 768 + (u + 1) * 32 + n];
        int byo = (n * 768 + kp * 4) ^ ((n & 7) << 4);
        *(int*)(BvL + byo) = pack_trunc(w0, w1);
    }

    // ---------------- per-edge prep (each lane: its tile-row edge) --------
    const int eloc = wv * 16 + mrow;       // 0..63
    const int e = blockIdx.x * 64 + eloc;
    const bool val = (e < E);
    const int ecl = val ? e : (E - 1);
    const int sidx = esrc[ecl];
    const int d = edst[ecl];

    float ev0 = pos[sidx * 3 + 0] - pos[d * 3 + 0];
    float ev1 = pos[sidx * 3 + 1] - pos[d * 3 + 1];
    float ev2 = pos[sidx * 3 + 2] - pos[d * 3 + 2];
    float len2 = ev0 * ev0 + ev1 * ev1 + ev2 * ev2 + 1e-12f;
    float elen = sqrtf(len2);
    float inv = 1.0f / elen;

    // Radial basis: support width 2 -> at most 2 non-zero components.
    float ttv = elen * 2.75f;
    int fi2 = (int)floorf(ttv);
    int ia = fi2 - 1, ib = fi2;
    float ea = 0.f, eb = 0.f;
    {
        float a = ttv - (float)ia, b = (float)(ia + 2) - ttv;
        if (ia >= 0 && ia < NBASIS && a > 0.f && b > 0.f)
            ea = CC * expf(-1.f / a - 1.f / b);
    }
    {
        float a = ttv - (float)ib, b = (float)(ib + 2) - ttv;
        if (ib >= 0 && ib < NBASIS && b > 0.f && a > 0.f)
            eb = CC * expf(-1.f / a - 1.f / b);
    }
    int ja = (ia >= 0 && ia < NBASIS) ? ia : 0;
    int jb = (ib >= 0 && ib < NBASIS) ? ib : 0;

    // Only the 4 h-channels this lane ever feeds: c = 4q + g, q = 0..3.
    float hkg[4], hvg[4];
#pragma unroll
    for (int q = 0; q < 4; ++q) {
        int c = 4 * q + g;
        float ak = (ea * Wk1[ja * 16 + c] + eb * Wk1[jb * 16 + c]) * INV_SQRT10;
        float av = (ea * Wv1[ja * 16 + c] + eb * Wv1[jb * 16 + c]) * INV_SQRT10;
        hkg[q] = ak / (1.f + expf(-ak));
        hvg[q] = av / (1.f + expf(-av));
    }

    // f = [x0_src (16), x1dot (8)]
    float f[24];
    const float* xr = x + (size_t)sidx * XDIM;
#pragma unroll
    for (int u = 0; u < MUL0; ++u) f[u] = xr[u];
#pragma unroll
    for (int u = 0; u < MUL1; ++u) {
        f[MUL0 + u] = (xr[16 + u * 3 + 0] * ev0 + xr[16 + u * 3 + 1] * ev1 +
                       xr[16 + u * 3 + 2] * ev2) * inv;
    }

    float argc = 10.f - 2.5f * elen;  // 10*(1 - elen/RMAX)
    float wcut = (argc > 0.f) ? expf(-1.f / argc) : 0.f;

    if (g == 0 && val) {
        dst_lds[eloc] = d;
        wcut_lds[eloc] = wcut;
        atomicAdd(&deg[d], 1);
    }

    __syncthreads();

    // ---------------- GEMM: 12 K-steps of 16x16x32 bf16 MFMA -------------
    const int swz = (mrow & 7) << 4;
    const int bkbase = mrow * 768 + g * 16;
    const int bv1base = (mrow + 16) * 768 + g * 16;

    f32x4 acck = {0.f, 0.f, 0.f, 0.f};
    f32x4 accv0 = {0.f, 0.f, 0.f, 0.f};
    f32x4 accv1 = {0.f, 0.f, 0.f, 0.f};

    auto STEP = [&](auto SC) {
        constexpr int S = decltype(SC)::value;
        constexpr int o8 = (S >> 2) * 8;   // f-octet base (compile-time)
        constexpr int q = S & 3;           // h-table index (compile-time)
        const float hks = hkg[q], hvs = hvg[q];
        float gk[8], gv[8], lk[8];
#pragma unroll
        for (int i = 0; i < 8; ++i) {
            float fi = f[o8 + i];
            gk[i] = hks * fi;
            gv[i] = hvs * fi;
            lk[i] = gk[i] - hi_part(gk[i]);
        }
        Frag akhi, aklo, av;
#pragma unroll
        for (int j = 0; j < 4; ++j) {
            akhi.i[j] = pack_trunc(gk[2 * j], gk[2 * j + 1]);
            aklo.i[j] = pack_trunc(lk[2 * j], lk[2 * j + 1]);
            av.i[j] = pack_trunc(gv[2 * j], gv[2 * j + 1]);
        }
        const short8 bkhi = *(const short8*)(BkHi + ((bkbase + S * 64) ^ swz));
        const short8 bklo = *(const short8*)(BkLo + ((bkbase + S * 64) ^ swz));
        const short8 bv0 = *(const short8*)(BvL + ((bkbase + S * 64) ^ swz));
        const short8 bv1 = *(const short8*)(BvL + ((bv1base + S * 64) ^ swz));
        acck = __builtin_amdgcn_mfma_f32_16x16x32_bf16(akhi.v, bkhi, acck, 0, 0, 0);
        acck = __builtin_amdgcn_mfma_f32_16x16x32_bf16(aklo.v, bkhi, acck, 0, 0, 0);
        acck = __builtin_amdgcn_mfma_f32_16x16x32_bf16(akhi.v, bklo, acck, 0, 0, 0);
        accv0 = __builtin_amdgcn_mfma_f32_16x16x32_bf16(av.v, bv0, accv0, 0, 0, 0);
        accv1 = __builtin_amdgcn_mfma_f32_16x16x32_bf16(av.v, bv1, accv1, 0, 0, 0);
    };
    STEP(IC<0>{});  STEP(IC<1>{});  STEP(IC<2>{});  STEP(IC<3>{});
    STEP(IC<4>{});  STEP(IC<5>{});  STEP(IC<6>{});  STEP(IC<7>{});
    STEP(IC<8>{});  STEP(IC<9>{});  STEP(IC<10>{}); STEP(IC<11>{});

    // ---------------- epilogue -------------------------------------------
    // C layout (verified): col = lane&15 (=w), row = g*4 + reg (=edge).
    float logit[4];
#pragma unroll
    for (int r = 0; r < 4; ++r) {
        int el2 = wv * 16 + g * 4 + r;
        int dr = dst_lds[el2];
        float p = qd[(size_t)dr * DK + mrow] * acck[r];
        p += __shfl_xor(p, 1);
        p += __shfl_xor(p, 2);
        p += __shfl_xor(p, 4);
        p += __shfl_xor(p, 8);
        logit[r] = p * KV_SCALE;
    }
#pragma unroll
    for (int r = 0; r < 4; ++r) {
        int el2 = wv * 16 + g * 4 + r;
        int eg = blockIdx.x * 64 + el2;
        if (mrow == r && eg < E) {
            float expv = wcut_lds[el2] * expf(logit[r]);
            expvbuf[eg] = expv;
            if (expv != 0.f) atomicAdd(&zbuf[dst_lds[el2]], expv);
        }
    }
#pragma unroll
    for (int r = 0; r < 4; ++r) {
        int eg = blockIdx.x * 64 + wv * 16 + g * 4 + r;
        if (eg < E) {
            vbuf[(size_t)eg * DV + mrow] = accv0[r] * KV_SCALE;
            vbuf[(size_t)eg * DV + 16 + mrow] = accv1[r] * KV_SCALE;
        }
    }
}

// Single-block exclusive scan of deg[0..N) -> start[0..N], start[N] = total.
__global__ __launch_bounds__(1024) void scan_kernel(const int* __restrict__ deg,
                                                    int* __restrict__ start, int N) {
    __shared__ int lds[1024];
    const int tid = threadIdx.x;
    const int chunk = (N + 1023) / 1024;
    const int lo = tid * chunk;
    const int hi = min(N, lo + chunk);
    int s = 0;
    for (int i = lo; i < hi; ++i) s += deg[i];
    lds[tid] = s;
    __syncthreads();
    for (int off = 1; off < 1024; off <<= 1) {
        int v = (tid >= off) ? lds[tid - off] : 0;
        __syncthreads();
        lds[tid] += v;
        __syncthreads();
    }
    int running = lds[tid] - s;  // exclusive base for this chunk
    for (int i = lo; i < hi; ++i) {
        start[i] = running;
        running += deg[i];
    }
    if (tid == 1023) start[N] = lds[1023];
}

__global__ void fill_kernel(const int* __restrict__ edst,
                            const int* __restrict__ start,
                            int* __restrict__ cursor,
                            int* __restrict__ bucket, int E) {
    int e = blockIdx.x * blockDim.x + threadIdx.x;
    if (e >= E) return;
    int d = edst[e];
    int p = atomicAdd(&cursor[d], 1);
    bucket[start[d] + p] = e;
}

// 32 lanes per node, one lane per output column. No atomics.
__global__ __launch_bounds__(256) void gather_kernel(
    const float* __restrict__ expvbuf, const float* __restrict__ vbuf,
    const float* __restrict__ zbuf, const int* __restrict__ start,
    const int* __restrict__ bucket, float* __restrict__ out, int N) {
    int n = blockIdx.x * 8 + (threadIdx.x >> 5);
    int w = threadIdx.x & 31;
    if (n >= N) return;
    float z = zbuf[n];
    if (z == 0.f) z = 1.f;
    float rz = 1.0f / z;
    int lo = start[n], hi = start[n + 1];
    float acc = 0.f;
    for (int i = lo; i < hi; ++i) {
        int e = bucket[i];                 // broadcast across 32 lanes
        float ev = expvbuf[e];             // broadcast
        float sa = sqrtf(ev * rz);
        acc += sa * vbuf[(size_t)e * DV + w];  // coalesced across lanes
    }
    out[(size_t)n * DV + w] = acc;
}

extern "C" void kernel_launch(void* const* d_in, const int* in_sizes, int n_in,
                              void* d_out, int out_size, void* d_ws, size_t ws_size,
                              hipStream_t stream) {
    const float* x    = (const float*)d_in[0];
    const float* pos  = (const float*)d_in[1];
    const float* Wq   = (const float*)d_in[2];
    const float* Wk1  = (const float*)d_in[3];
    const float* Wk2  = (const float*)d_in[4];
    const float* Wv1  = (const float*)d_in[5];
    const float* Wv2  = (const float*)d_in[6];
    const float* Wdot = (const float*)d_in[7];
    const int* esrc   = (const int*)d_in[8];
    const int* edst   = (const int*)d_in[9];

    const int N = in_sizes[0] / XDIM;
    const int E = in_sizes[8];

    float* out = (float*)d_out;

    // workspace layout (all 4-byte elements)
    float* qd      = (float*)d_ws;              // N*16
    float* zbuf    = qd + (size_t)N * DK;       // N      } contiguous zero
    int*   deg     = (int*)(zbuf + N);          // N      } block: one
    int*   cursor  = deg + N;                   // N      } memset
    int*   start   = cursor + N;                // N+1
    int*   bucket  = start + N + 1;             // E
    float* expvbuf = (float*)(bucket + E);      // E
    float* vbuf    = expvbuf + E;               // E*32

    hipMemsetAsync(zbuf, 0, (size_t)(3 * N) * sizeof(int), stream);

    {
        int bs = 256, gs = (N + bs - 1) / bs;
        node_qd_kernel<<<gs, bs, 0, stream>>>(x, Wq, Wdot, qd, N);
    }
    {
        int gs = (E + 63) / 64;
        edge_kernel<<<gs, 256, 0, stream>>>(x, pos, Wk1, Wk2, Wv1, Wv2, qd,
                                            esrc, edst, zbuf, expvbuf, vbuf, deg, E);
    }
    scan_kernel<<<1, 1024, 0, stream>>>(deg, start, N);
    {
        int bs = 256, gs = (E + bs - 1) / bs;
        fill_kernel<<<gs, bs, 0, stream>>>(edst, start, cursor, bucket, E);
    }
    {
        int bs = 256, gs = (N + 7) / 8;
        gather_kernel<<<gs, bs, 0, stream>>>(expvbuf, vbuf, zbuf, start, bucket, out, N);
    }
}

// Round 6
// 108.405 us; speedup vs baseline: 9.9650x; 1.1133x over previous
//
#include <hip/hip_runtime.h>

// GraphSelfAttention: E3NN-style graph attention.
// N=20000 nodes, E=120000 edges, MUL0=16, MUL1=8, NB=10, DK=16, DV=32.
// Round 6: (a) weight bf16-conversion hoisted to one-time prep writing the
// exact swizzled 48KB LDS image; edge blocks stage it via global_load_lds
// (width 16, linear dest == pre-swizzled source) -> staging VALU ~0, staging
// bank conflicts 0. (b) tail fused: qd+prep+deg in one launch, CSR-fill moved
// into edge epilogue, z computed inside gather (zbuf atomics removed).

#define MUL0 16
#define MUL1 8
#define NBASIS 10
#define DK 16
#define DV 32
#define XDIM 40   // MUL0 + 3*MUL1

#define CC 26.6692987f          // 1.14136 * e^2 * sqrt(10)
#define INV_SQRT10 0.3162277660f
#define KV_SCALE 0.0510310363f  // 1/(4*sqrt(24))

typedef short short8 __attribute__((ext_vector_type(8)));
typedef float f32x4 __attribute__((ext_vector_type(4)));

union Frag { int i[4]; short8 v; };

template <int N> struct IC { static constexpr int value = N; };

__device__ __forceinline__ float hi_part(float x) {
    unsigned u = __builtin_bit_cast(unsigned, x) & 0xFFFF0000u;
    return __builtin_bit_cast(float, u);
}
// pack {lo16=bf16(a), hi16=bf16(b)} via byte-perm (truncation)
__device__ __forceinline__ int pack_trunc(float a, float b) {
    return (int)__builtin_amdgcn_perm(__builtin_bit_cast(unsigned, b),
                                      __builtin_bit_cast(unsigned, a),
                                      0x07060302u);
}

typedef const __attribute__((address_space(1))) void gconst_void;
typedef __attribute__((address_space(3))) void lds_void;
__device__ __forceinline__ void gload_lds16(const void* g, void* l) {
    __builtin_amdgcn_global_load_lds((gconst_void*)g, (lds_void*)l, 16, 0, 0);
}

// Fused: block 0 converts Wk2/Wv2 into the swizzled bf16 blob (48 KB);
// blocks [1, 1+qdB) compute qd; blocks [1+qdB, ...) histogram deg.
__global__ __launch_bounds__(256) void prep_kernel(
    const float* __restrict__ x, const float* __restrict__ Wq,
    const float* __restrict__ Wdot, const float* __restrict__ Wk2,
    const float* __restrict__ Wv2, const int* __restrict__ edst,
    float* __restrict__ qd, char* __restrict__ blob, int* __restrict__ deg,
    int N, int E, int qdB) {
    const int tid = threadIdx.x;
    const int b = blockIdx.x;
    if (b == 0) {
        // K-order: k' = s*32+g*8+i <-> (c = 4(s&3)+g, u = 8(s>>2)+i)
        for (int i = tid; i < 3072; i += 256) {
            int n = i & 15, kp = i >> 4;             // kp in [0,192)
            int s = kp >> 4, g2 = (kp >> 2) & 3, i2 = (kp & 3) * 2;
            int c = 4 * (s & 3) + g2;
            int u = 8 * (s >> 2) + i2;
            float w0 = Wk2[c * 384 + u * 16 + n];
            float w1 = Wk2[c * 384 + (u + 1) * 16 + n];
            int byo = (n * 768 + kp * 4) ^ ((n & 7) << 4);
            *(int*)(blob + byo) = pack_trunc(w0, w1);
            *(int*)(blob + 12288 + byo) =
                pack_trunc(w0 - hi_part(w0), w1 - hi_part(w1));
        }
        for (int i = tid; i < 6144; i += 256) {
            int n = i & 31, kp = i >> 5;
            int s = kp >> 4, g2 = (kp >> 2) & 3, i2 = (kp & 3) * 2;
            int c = 4 * (s & 3) + g2;
            int u = 8 * (s >> 2) + i2;
            float w0 = Wv2[c * 768 + u * 32 + n];
            float w1 = Wv2[c * 768 + (u + 1) * 32 + n];
            int byo = (n * 768 + kp * 4) ^ ((n & 7) << 4);
            *(int*)(blob + 24576 + byo) = pack_trunc(w0, w1);
        }
    } else if (b <= qdB) {
        int n = (b - 1) * 256 + tid;
        if (n < N) {
            const float* xr = x + (size_t)n * XDIM;
            float x0[MUL0];
#pragma unroll
            for (int u = 0; u < MUL0; ++u) x0[u] = xr[u];
            float q[DK];
#pragma unroll
            for (int w = 0; w < DK; ++w) {
                float a = 0.f;
#pragma unroll
                for (int u = 0; u < MUL0; ++u) a += x0[u] * Wq[u * DK + w];
                q[w] = a * 0.25f;  // /sqrt(16)
            }
#pragma unroll
            for (int w = 0; w < DK; ++w) {
                float a = 0.f;
#pragma unroll
                for (int u = 0; u < DK; ++u) a += q[u] * Wdot[u * DK + w];
                qd[(size_t)n * DK + w] = a * 0.0625f;  // /MUL0
            }
        }
    } else {
        int e = (b - 1 - qdB) * 256 + tid;
        if (e < E) atomicAdd(&deg[edst[e]], 1);
    }
}

// Block = 256 threads = 4 waves; block owns 64 edges (wave: 16-edge M-tile).
__global__ __launch_bounds__(256) void edge_kernel(
    const float* __restrict__ x, const float* __restrict__ pos,
    const float* __restrict__ Wk1, const float* __restrict__ Wv1,
    const float* __restrict__ qd, const char* __restrict__ blob,
    const int* __restrict__ esrc, const int* __restrict__ edst,
    const int* __restrict__ start, int* __restrict__ cursor,
    float* __restrict__ expvbuf, float* __restrict__ vbuf,
    int* __restrict__ bucket, int E) {
    __shared__ char Blds[49152];   // BkHi | BkLo | BvL (swizzled bf16 image)
    __shared__ int dst_lds[64];
    __shared__ float wcut_lds[64];

    const int tid = threadIdx.x;
    const int wv = tid >> 6;
    const int lane = tid & 63;
    const int mrow = lane & 15;     // edge row within tile / output col
    const int g = lane >> 4;        // k-group

    // Async-stage the preconverted 48KB weight image (linear copy: the blob
    // already holds the swizzled layout). DMA overlaps the per-edge prep.
    {
        const char* gsrc = blob + wv * 12288 + lane * 16;
        char* ldst = Blds + wv * 12288;
#pragma unroll
        for (int it = 0; it < 12; ++it)
            gload_lds16(gsrc + it * 1024, ldst + it * 1024);
    }

    // ---------------- per-edge prep (each lane: its tile-row edge) --------
    const int eloc = wv * 16 + mrow;       // 0..63
    const int e = blockIdx.x * 64 + eloc;
    const bool val = (e < E);
    const int ecl = val ? e : (E - 1);
    const int sidx = esrc[ecl];
    const int d = edst[ecl];

    float ev0 = pos[sidx * 3 + 0] - pos[d * 3 + 0];
    float ev1 = pos[sidx * 3 + 1] - pos[d * 3 + 1];
    float ev2 = pos[sidx * 3 + 2] - pos[d * 3 + 2];
    float len2 = ev0 * ev0 + ev1 * ev1 + ev2 * ev2 + 1e-12f;
    float elen = sqrtf(len2);
    float inv = 1.0f / elen;

    // Radial basis: support width 2 -> at most 2 non-zero components.
    float ttv = elen * 2.75f;
    int fi2 = (int)floorf(ttv);
    int ia = fi2 - 1, ib = fi2;
    float ea = 0.f, eb = 0.f;
    {
        float a = ttv - (float)ia, b = (float)(ia + 2) - ttv;
        if (ia >= 0 && ia < NBASIS && a > 0.f && b > 0.f)
            ea = CC * expf(-1.f / a - 1.f / b);
    }
    {
        float a = ttv - (float)ib, b = (float)(ib + 2) - ttv;
        if (ib >= 0 && ib < NBASIS && b > 0.f && a > 0.f)
            eb = CC * expf(-1.f / a - 1.f / b);
    }
    int ja = (ia >= 0 && ia < NBASIS) ? ia : 0;
    int jb = (ib >= 0 && ib < NBASIS) ? ib : 0;

    // Only the 4 h-channels this lane feeds: c = 4q + g, q = 0..3.
    float hkg[4], hvg[4];
#pragma unroll
    for (int q = 0; q < 4; ++q) {
        int c = 4 * q + g;
        float ak = (ea * Wk1[ja * 16 + c] + eb * Wk1[jb * 16 + c]) * INV_SQRT10;
        float av = (ea * Wv1[ja * 16 + c] + eb * Wv1[jb * 16 + c]) * INV_SQRT10;
        hkg[q] = ak / (1.f + expf(-ak));
        hvg[q] = av / (1.f + expf(-av));
    }

    // f = [x0_src (16), x1dot (8)]
    float f[24];
    const float* xr = x + (size_t)sidx * XDIM;
#pragma unroll
    for (int u = 0; u < MUL0; ++u) f[u] = xr[u];
#pragma unroll
    for (int u = 0; u < MUL1; ++u) {
        f[MUL0 + u] = (xr[16 + u * 3 + 0] * ev0 + xr[16 + u * 3 + 1] * ev1 +
                       xr[16 + u * 3 + 2] * ev2) * inv;
    }

    float argc = 10.f - 2.5f * elen;  // 10*(1 - elen/RMAX)
    float wcut = (argc > 0.f) ? expf(-1.f / argc) : 0.f;

    if (g == 0 && val) {
        dst_lds[eloc] = d;
        wcut_lds[eloc] = wcut;
    }

    __syncthreads();  // drains the global_load_lds DMA + dst/wcut writes

    // ---------------- GEMM: 12 K-steps of 16x16x32 bf16 MFMA -------------
    const char* BkHi = Blds;
    const char* BkLo = Blds + 12288;
    const char* BvL  = Blds + 24576;
    const int swz = (mrow & 7) << 4;
    const int bkbase = mrow * 768 + g * 16;
    const int bv1base = (mrow + 16) * 768 + g * 16;

    f32x4 acck = {0.f, 0.f, 0.f, 0.f};
    f32x4 accv0 = {0.f, 0.f, 0.f, 0.f};
    f32x4 accv1 = {0.f, 0.f, 0.f, 0.f};

    auto STEP = [&](auto SC) {
        constexpr int S = decltype(SC)::value;
        constexpr int o8 = (S >> 2) * 8;   // f-octet base (compile-time)
        constexpr int q = S & 3;           // h-table index (compile-time)
        const float hks = hkg[q], hvs = hvg[q];
        float gk[8], gv[8], lk[8];
#pragma unroll
        for (int i = 0; i < 8; ++i) {
            float fi = f[o8 + i];
            gk[i] = hks * fi;
            gv[i] = hvs * fi;
            lk[i] = gk[i] - hi_part(gk[i]);
        }
        Frag akhi, aklo, av;
#pragma unroll
        for (int j = 0; j < 4; ++j) {
            akhi.i[j] = pack_trunc(gk[2 * j], gk[2 * j + 1]);
            aklo.i[j] = pack_trunc(lk[2 * j], lk[2 * j + 1]);
            av.i[j] = pack_trunc(gv[2 * j], gv[2 * j + 1]);
        }
        const short8 bkhi = *(const short8*)(BkHi + ((bkbase + S * 64) ^ swz));
        const short8 bklo = *(const short8*)(BkLo + ((bkbase + S * 64) ^ swz));
        const short8 bv0 = *(const short8*)(BvL + ((bkbase + S * 64) ^ swz));
        const short8 bv1 = *(const short8*)(BvL + ((bv1base + S * 64) ^ swz));
        acck = __builtin_amdgcn_mfma_f32_16x16x32_bf16(akhi.v, bkhi, acck, 0, 0, 0);
        acck = __builtin_amdgcn_mfma_f32_16x16x32_bf16(aklo.v, bkhi, acck, 0, 0, 0);
        acck = __builtin_amdgcn_mfma_f32_16x16x32_bf16(akhi.v, bklo, acck, 0, 0, 0);
        accv0 = __builtin_amdgcn_mfma_f32_16x16x32_bf16(av.v, bv0, accv0, 0, 0, 0);
        accv1 = __builtin_amdgcn_mfma_f32_16x16x32_bf16(av.v, bv1, accv1, 0, 0, 0);
    };
    STEP(IC<0>{});  STEP(IC<1>{});  STEP(IC<2>{});  STEP(IC<3>{});
    STEP(IC<4>{});  STEP(IC<5>{});  STEP(IC<6>{});  STEP(IC<7>{});
    STEP(IC<8>{});  STEP(IC<9>{});  STEP(IC<10>{}); STEP(IC<11>{});

    // ---------------- epilogue -------------------------------------------
    // C layout: col = lane&15 (=w), row = g*4 + reg (=edge within wave tile).
    float logit[4];
#pragma unroll
    for (int r = 0; r < 4; ++r) {
        int el2 = wv * 16 + g * 4 + r;
        int dr = dst_lds[el2];
        float p = qd[(size_t)dr * DK + mrow] * acck[r];
        p += __shfl_xor(p, 1);
        p += __shfl_xor(p, 2);
        p += __shfl_xor(p, 4);
        p += __shfl_xor(p, 8);
        logit[r] = p * KV_SCALE;
    }
#pragma unroll
    for (int r = 0; r < 4; ++r) {
        int el2 = wv * 16 + g * 4 + r;
        int eg = blockIdx.x * 64 + el2;
        if (mrow == r && eg < E) {
            float expv = wcut_lds[el2] * expf(logit[r]);
            expvbuf[eg] = expv;
            int dr = dst_lds[el2];
            int p = atomicAdd(&cursor[dr], 1);   // CSR fill (fused)
            bucket[start[dr] + p] = eg;
        }
    }
#pragma unroll
    for (int r = 0; r < 4; ++r) {
        int eg = blockIdx.x * 64 + wv * 16 + g * 4 + r;
        if (eg < E) {
            vbuf[(size_t)eg * DV + mrow] = accv0[r] * KV_SCALE;
            vbuf[(size_t)eg * DV + 16 + mrow] = accv1[r] * KV_SCALE;
        }
    }
}

// Single-block exclusive scan of deg[0..N) -> start[0..N].
__global__ __launch_bounds__(1024) void scan_kernel(const int* __restrict__ deg,
                                                    int* __restrict__ start, int N) {
    __shared__ int lds[1024];
    const int tid = threadIdx.x;
    const int chunk = (N + 1023) / 1024;
    const int lo = tid * chunk;
    const int hi = min(N, lo + chunk);
    int s = 0;
    for (int i = lo; i < hi; ++i) s += deg[i];
    lds[tid] = s;
    __syncthreads();
    for (int off = 1; off < 1024; off <<= 1) {
        int v = (tid >= off) ? lds[tid - off] : 0;
        __syncthreads();
        lds[tid] += v;
        __syncthreads();
    }
    int running = lds[tid] - s;  // exclusive base for this chunk
    for (int i = lo; i < hi; ++i) {
        start[i] = running;
        running += deg[i];
    }
    if (tid == 1023) start[N] = lds[1023];
}

// 32 lanes per node, one lane per output column. z computed in-kernel.
__global__ __launch_bounds__(256) void gather_kernel(
    const float* __restrict__ expvbuf, const float* __restrict__ vbuf,
    const int* __restrict__ deg, const int* __restrict__ start,
    const int* __restrict__ bucket, float* __restrict__ out, int N) {
    int n = blockIdx.x * 8 + (threadIdx.x >> 5);
    int w = threadIdx.x & 31;
    if (n >= N) return;
    int lo = start[n], cnt = deg[n];
    float z = 0.f;
    for (int i = 0; i < cnt; ++i) z += expvbuf[bucket[lo + i]];
    if (z == 0.f) z = 1.f;
    float rz = 1.0f / z;
    float acc = 0.f;
    for (int i = 0; i < cnt; ++i) {
        int e = bucket[lo + i];                // broadcast across 32 lanes
        float sa = sqrtf(expvbuf[e] * rz);
        acc += sa * vbuf[(size_t)e * DV + w];  // coalesced across lanes
    }
    out[(size_t)n * DV + w] = acc;
}

extern "C" void kernel_launch(void* const* d_in, const int* in_sizes, int n_in,
                              void* d_out, int out_size, void* d_ws, size_t ws_size,
                              hipStream_t stream) {
    const float* x    = (const float*)d_in[0];
    const float* pos  = (const float*)d_in[1];
    const float* Wq   = (const float*)d_in[2];
    const float* Wk1  = (const float*)d_in[3];
    const float* Wk2  = (const float*)d_in[4];
    const float* Wv1  = (const float*)d_in[5];
    const float* Wv2  = (const float*)d_in[6];
    const float* Wdot = (const float*)d_in[7];
    const int* esrc   = (const int*)d_in[8];
    const int* edst   = (const int*)d_in[9];

    const int N = in_sizes[0] / XDIM;
    const int E = in_sizes[8];

    float* out = (float*)d_out;

    // workspace layout (4-byte elements unless noted)
    float* qd      = (float*)d_ws;              // N*16
    int*   deg     = (int*)(qd + (size_t)N * DK); // N   } contiguous zero
    int*   cursor  = deg + N;                   // N    } block: one memset
    int*   start   = cursor + N;                // N+1
    int*   bucket  = start + N + 1;             // E
    float* expvbuf = (float*)(bucket + E);      // E
    float* vbuf    = expvbuf + E;               // E*32
    char*  blob    = (char*)(vbuf + (size_t)E * DV); // 49152 bytes

    hipMemsetAsync(deg, 0, (size_t)(2 * N) * sizeof(int), stream);

    const int qdB = (N + 255) / 256;
    const int degB = (E + 255) / 256;
    prep_kernel<<<1 + qdB + degB, 256, 0, stream>>>(
        x, Wq, Wdot, Wk2, Wv2, edst, qd, blob, deg, N, E, qdB);
    scan_kernel<<<1, 1024, 0, stream>>>(deg, start, N);
    {
        int gs = (E + 63) / 64;
        edge_kernel<<<gs, 256, 0, stream>>>(x, pos, Wk1, Wv1, qd, blob,
                                            esrc, edst, start, cursor,
                                            expvbuf, vbuf, bucket, E);
    }
    {
        int gs = (N + 7) / 8;
        gather_kernel<<<gs, 256, 0, stream>>>(expvbuf, vbuf, deg, start,
                                              bucket, out, N);
    }
}